// Round 1
// baseline (51.479 us; speedup 1.0000x reference)
//
#include <hip/hip_runtime.h>

#define NROWS  50000
#define NF     32
#define NTREES 300
#define NINT   63
#define NLEAF  64
#define LRATE  0.1f
#define RPB    256     // rows per block == threads per block
#define TG     10      // tree groups (grid.y)
#define TPG    30      // trees per group (multiple of 3 classes)

__global__ void gb_init_out(const float* __restrict__ initp,
                            float* __restrict__ out, int n) {
    int i = blockIdx.x * blockDim.x + threadIdx.x;
    if (i < n) out[i] = initp[i % 3];
}

__global__ __launch_bounds__(RPB) void gb_forest(
    const float* __restrict__ x,      // [NROWS][NF]
    const int*   __restrict__ feat,   // [NTREES][NINT]
    const float* __restrict__ thr,    // [NTREES][NINT]
    const float* __restrict__ leaves, // [NTREES][NLEAF]
    float*       __restrict__ out)    // [NROWS][3]
{
    __shared__ float xs[NF][RPB];        // 32 KB, transposed: bank = tid%32, conflict-free
    __shared__ int2  nodes[TPG][64];     // 15 KB packed {feature, threshold_bits}

    const int tid = threadIdx.x;
    const int r0  = blockIdx.x * RPB;
    const int m0  = blockIdx.y * TPG;

    // --- stage x transposed; global reads fully coalesced (8 lanes = one 128B row) ---
    {
        const float4* x4 = (const float4*)x;
        #pragma unroll
        for (int k = 0; k < 8; ++k) {
            int i    = tid + k * RPB;
            int row  = i >> 3;      // 0..255
            int f4   = i & 7;       // 0..7
            int grow = r0 + row;
            float4 v = make_float4(0.f, 0.f, 0.f, 0.f);
            if (grow < NROWS) v = x4[grow * (NF / 4) + f4];
            xs[f4 * 4 + 0][row] = v.x;
            xs[f4 * 4 + 1][row] = v.y;
            xs[f4 * 4 + 2][row] = v.z;
            xs[f4 * 4 + 3][row] = v.w;
        }
    }
    // --- stage this group's tree nodes packed into LDS ---
    for (int i = tid; i < TPG * NINT; i += RPB) {
        int tl = i / NINT;
        int nd = i - tl * NINT;
        int gi = (m0 + tl) * NINT + nd;
        nodes[tl][nd] = make_int2(feat[gi], __float_as_int(thr[gi]));
    }
    __syncthreads();

    // --- walk 3 trees at a time (classes 0,1,2), 6 levels each ---
    float acc0 = 0.f, acc1 = 0.f, acc2 = 0.f;
    for (int it = 0; it < TPG; it += 3) {
        int ia = 0, ib = 0, ic = 0;
        const int2* __restrict__ na = nodes[it];
        const int2* __restrict__ nb = nodes[it + 1];
        const int2* __restrict__ nc = nodes[it + 2];
        #pragma unroll
        for (int d = 0; d < 6; ++d) {
            int2 A = na[ia];
            int2 B = nb[ib];
            int2 C = nc[ic];
            float xa = xs[A.x][tid];
            float xb = xs[B.x][tid];
            float xc = xs[C.x][tid];
            // sklearn: left (+1) iff x <= t, right (+2) otherwise
            ia = 2 * ia + 1 + (xa > __int_as_float(A.y) ? 1 : 0);
            ib = 2 * ib + 1 + (xb > __int_as_float(B.y) ? 1 : 0);
            ic = 2 * ic + 1 + (xc > __int_as_float(C.y) ? 1 : 0);
        }
        acc0 += leaves[(m0 + it    ) * NLEAF + (ia - NINT)];
        acc1 += leaves[(m0 + it + 1) * NLEAF + (ib - NINT)];
        acc2 += leaves[(m0 + it + 2) * NLEAF + (ic - NINT)];
    }

    int grow = r0 + tid;
    if (grow < NROWS) {
        atomicAdd(&out[grow * 3 + 0], LRATE * acc0);
        atomicAdd(&out[grow * 3 + 1], LRATE * acc1);
        atomicAdd(&out[grow * 3 + 2], LRATE * acc2);
    }
}

extern "C" void kernel_launch(void* const* d_in, const int* in_sizes, int n_in,
                              void* d_out, int out_size, void* d_ws, size_t ws_size,
                              hipStream_t stream) {
    const float* x      = (const float*)d_in[0];
    const int*   feat   = (const int*)d_in[1];
    const float* thr    = (const float*)d_in[2];
    const float* leaves = (const float*)d_in[3];
    const float* initp  = (const float*)d_in[4];
    float* out = (float*)d_out;

    gb_init_out<<<(out_size + 255) / 256, 256, 0, stream>>>(initp, out, out_size);

    dim3 grid((NROWS + RPB - 1) / RPB, TG);
    gb_forest<<<grid, RPB, 0, stream>>>(x, feat, thr, leaves, out);
}